// Round 8
// baseline (4266.553 us; speedup 1.0000x reference)
//
#include <hip/hip_runtime.h>
#include <hip/hip_bf16.h>

#define B_ 4
#define T_ 300
#define U_ 64
#define U1_ 65
#define V_ 1024
#define H_ 512
#define G4_ 2048
#define NW_ 32
#define RPB_ (T_ * U1_)   // 19500 rows per batch in joint
#define NTILE_ 305        // ceil(19500/64)
#define RPAD_ 19520       // NTILE_*64

typedef __hip_bfloat16 bf16;
typedef unsigned long long u64;
typedef __attribute__((ext_vector_type(8))) short short8;
typedef __attribute__((ext_vector_type(4))) float floatx4;

__device__ __forceinline__ float b2f(bf16 x) { return __bfloat162float(x); }
__device__ __forceinline__ bf16 f2b(float x) { return __float2bfloat16(x); }
__device__ __forceinline__ short bf16bits(float x) {
  bf16 h = __float2bfloat16(x);
  return *reinterpret_cast<short*>(&h);
}
__device__ __forceinline__ short8 pack8(float4 a, float4 b) {
  short8 p;
  p[0] = bf16bits(a.x); p[1] = bf16bits(a.y); p[2] = bf16bits(a.z); p[3] = bf16bits(a.w);
  p[4] = bf16bits(b.x); p[5] = bf16bits(b.y); p[6] = bf16bits(b.z); p[7] = bf16bits(b.w);
  return p;
}
__device__ __forceinline__ float sigm_(float x) { return 1.f / (1.f + __expf(-x)); }
__device__ __forceinline__ float tanh_(float x) { return 1.f - 2.f / (1.f + __expf(2.f * x)); }
__device__ __forceinline__ float lae_(float x, float y) {
  float m = fmaxf(x, y);
  float n = fminf(x, y);
  return m + __logf(1.f + __expf(n - m));
}

// ---------------- zero payload + counters (stale state from prior launches)
__global__ void zero_hpk_kernel(float* __restrict__ pay, unsigned* __restrict__ cnt) {
  int i = blockIdx.x * 256 + threadIdx.x;
  if (i < 7 * 4096) pay[i] = 0.f;
  if (i < 7 * 64) cnt[i] = 0u;
}

// ---------------- prep: pad layer-0 input (80 -> 128 cols of a 1024-stride buf)
__global__ void prep_kernel(const float* __restrict__ in, bf16* __restrict__ x0) {
  int i = blockIdx.x * 256 + threadIdx.x;
  if (i < B_ * T_ * 128) {
    int k = i & 127;
    int row = i >> 7;
    float v = (k < 80) ? in[row * 80 + k] : 0.f;
    x0[(size_t)row * 1024 + k] = f2b(v);
  }
}

// ---------------- embedding gather (f32 table -> bf16)
__global__ void embed_kernel(const float* __restrict__ emb, const int* __restrict__ tgt,
                             bf16* __restrict__ demb) {
  int i = blockIdx.x * 256 + threadIdx.x;
  if (i >= B_ * U1_ * 512) return;
  int k = i & 511;
  int bu = i >> 9;
  int u = bu % U1_, b = bu / U1_;
  int id = (u == 0) ? 0 : tgt[b * U_ + u - 1];
  demb[i] = f2b(emb[(size_t)id * 512 + k]);
}

// ---------------- bf16-A x f32-W MFMA GEMM: C[M x (grid.y*64)] = A[M,K] @ W[N,K]^T + bias
__global__ __launch_bounds__(256) void gemm_kernel(
    const bf16* __restrict__ A, int lda,
    const float* __restrict__ W, int ldw,
    const float* __restrict__ bias,
    void* __restrict__ Cout, int out_f32, int ldc,
    int M, int K) {
  __shared__ __align__(16) bf16 As[64][72];
  __shared__ __align__(16) bf16 Bs[64][72];
  int m0 = blockIdx.x * 64, n0 = blockIdx.y * 64;
  int tid = threadIdx.x, w = tid >> 6, l = tid & 63;
  int l4 = l & 15, lq = l >> 4;
  floatx4 acc[4];
#pragma unroll
  for (int nt = 0; nt < 4; ++nt) acc[nt] = (floatx4){0.f, 0.f, 0.f, 0.f};
  for (int k0 = 0; k0 < K; k0 += 64) {
    __syncthreads();
#pragma unroll
    for (int q = 0; q < 2; ++q) {
      int cc = tid + q * 256;
      int r = cc >> 3, kc = (cc & 7) * 8;
      short8 va = {0, 0, 0, 0, 0, 0, 0, 0};
      int gm = m0 + r;
      if (gm < M) va = *(const short8*)(A + (size_t)gm * lda + k0 + kc);
      *(short8*)(&As[r][kc]) = va;
      const float* wp = W + (size_t)(n0 + r) * ldw + k0 + kc;
      float4 w0 = *(const float4*)(wp);
      float4 w1 = *(const float4*)(wp + 4);
      *(short8*)(&Bs[r][kc]) = pack8(w0, w1);
    }
    __syncthreads();
#pragma unroll
    for (int kk = 0; kk < 64; kk += 32) {
      short8 a = *(const short8*)(&As[w * 16 + l4][kk + lq * 8]);
#pragma unroll
      for (int nt = 0; nt < 4; ++nt) {
        short8 bb = *(const short8*)(&Bs[nt * 16 + l4][kk + lq * 8]);
        acc[nt] = __builtin_amdgcn_mfma_f32_16x16x32_bf16(a, bb, acc[nt], 0, 0, 0);
      }
    }
  }
#pragma unroll
  for (int nt = 0; nt < 4; ++nt) {
    int col = n0 + nt * 16 + l4;
    float bv = bias ? bias[col] : 0.f;
#pragma unroll
    for (int r = 0; r < 4; ++r) {
      int row = m0 + w * 16 + lq * 4 + r;
      if (row < M) {
        float v = acc[nt][r] + bv;
        if (out_f32) ((float*)Cout)[(size_t)row * ldc + col] = v;
        else ((bf16*)Cout)[(size_t)row * ldc + col] = f2b(v);
      }
    }
  }
}

// ---------------- persistent LSTM scan (R6 body; counted-flag handoff).
// grid = (NW_, ndir). WG w owns h-dims [w*16,+16) x 4 gates; wave sub = one
// 16-col MFMA tile over full K=512; h split hi+lo bf16 (A rows 0-3/4-7) ->
// exact f32-accum matvec. xv gate-input loads double-buffered post-barrier
// (the R6 win).
// Handoff protocol (replaces per-packet stamp polling):
//   payload: f32 hpay[parity][b][dim], relaxed agent atomic stores.
//   producers: publish -> __syncthreads (pre-barrier s_waitcnt vmcnt(0)
//   drains ALL 4 waves' publishes to the coherence point — the same ordering
//   LLVM's gfx9 release model uses) -> tid0 relaxed fetch_add on per-dir cnt.
//   consumers: spin on ONE uniform dword (cnt >= NW_*s, monotonic, no reset),
//   then load payloads exactly once (relaxed agent u64 loads, stale-proof).
// Deadlock-safe: cnt incremented unconditionally every step by every WG.
// Ring-depth-2 safe: a WG reaches step s+1 (overwriting h(s-1)'s slot) only
// after cnt >= NW_*(s+1), i.e. after ALL WGs (incl. the slowest consumer)
// finished step s — which required consuming h(s-1) first.
__global__ __launch_bounds__(256, 1) void scan_kernel(
    const float* __restrict__ xg,      // [ndir][B][Tmax][2048] f32
    const float* __restrict__ whh,     // [ndir][2048][512] f32
    const int* __restrict__ len_raw, int len_add,
    int Tmax, int bwd_mask,
    bf16* __restrict__ out, int out_stride,
    int dec_d,
    const float* __restrict__ xg2, const float* __restrict__ whh2,
    const int* __restrict__ len_raw2, int len_add2,
    int Tmax2, bf16* __restrict__ out2, int out_stride2,
    float* __restrict__ hpay, unsigned* __restrict__ hcnt) {
  int w = blockIdx.x, d = blockIdx.y;
  int tid = threadIdx.x;
  bool isdec = (d == dec_d);
  const float* xg_d = isdec ? xg2 : xg + (size_t)d * B_ * Tmax * G4_;
  const float* whh_d = isdec ? whh2 : whh + (size_t)d * G4_ * H_;
  const int* lens = isdec ? len_raw2 : len_raw;
  int ladd = isdec ? len_add2 : len_add;
  int tmax = isdec ? Tmax2 : Tmax;
  bf16* outp = isdec ? out2 : out;
  int ostride = isdec ? out_stride2 : out_stride;
  int ocol = isdec ? 0 : d * H_;
  bool bwd = isdec ? false : ((bwd_mask >> d) & 1);
  float* pay = hpay + (size_t)d * 4096;       // [2][4][512] f32
  unsigned* cnt = hcnt + (size_t)d * 64;      // own 256B line per dir

  int sub = tid >> 6;          // wave index 0..3
  int l = tid & 63;
  int col = l & 15;            // MFMA output column (gate-row within wave tile)
  int lq = l >> 4;
  int gate = col & 3;          // col -> gate-major mapping: grow = gate*512+dim
  int dloc = col >> 2;
  int dim = w * 16 + sub * 4 + dloc;
  int grow = gate * H_ + dim;
  int sb = l & 12;             // shuffle base: lanes sb..sb+3 = 4 gates of one dim

  __shared__ int len_s[4];
  // A operand: rows 0-3 = h_hi (batch), rows 4-7 = h_lo (batch), rows 8-15 = 0.
  __shared__ __align__(16) bf16 h_lds[2][16][512];

  if (tid < 4) len_s[tid] = lens[tid] + ladd;
  {
    unsigned* hz = (unsigned*)&h_lds[0][0][0];
#pragma unroll
    for (int i = 0; i < 32; ++i) hz[tid + i * 256] = 0u;
  }

  // B fragments: Whh row 'grow' as bf16, 16 K-steps x 8 elems (64 VGPRs)
  short8 bfr[16];
  {
    const float* wp = whh_d + (size_t)grow * H_ + lq * 8;
#pragma unroll
    for (int ks2 = 0; ks2 < 16; ++ks2) {
      float4 w0 = *(const float4*)(wp + ks2 * 32);
      float4 w1 = *(const float4*)(wp + ks2 * 32 + 4);
      bfr[ks2] = pack8(w0, w1);
    }
  }
  __syncthreads();
  int smax = max(max(len_s[0], len_s[1]), max(len_s[2], len_s[3]));

  int D0 = sub * 128 + 2 * l;  // this lane consumes dims D0, D0+1 (adjacent)
  float cst = 0.f;             // cell state for (dim, batch = l&3) on lanes<16
  char* hbase = (char*)&h_lds[0][0][0];
  unsigned rsw = (unsigned)((l & 7) << 4);                 // read XOR swizzle
  unsigned rbyte = (unsigned)((l & 15) * 1024 + lq * 16);  // A-frag base byte

  // xv prologue for s=0 (gate input, all 4 batches, lanes<16)
  float xv[4];
  if (l < 16) {
#pragma unroll
    for (int b = 0; b < 4; ++b) {
      int lb = len_s[b];
      int rt = bwd ? (lb - 1) : 0;
      xv[b] = xg_d[((size_t)b * tmax + rt) * G4_ + grow];
    }
  }

  for (int s = 0; s < smax; ++s) {
    int p = s & 1;
    char* pl = hbase + p * 16384;
    // acquire h(s-1): spin on ONE uniform counter dword, then load payloads
    // exactly once (no per-packet stamps, no retry rounds)
    if (s > 0) {
      unsigned need = (unsigned)(NW_ * s);
      for (;;) {
        unsigned c = __hip_atomic_load(cnt, __ATOMIC_RELAXED, __HIP_MEMORY_SCOPE_AGENT);
        if (c >= need) break;
      }
      const u64* src = (const u64*)(pay + ((s - 1) & 1) * 2048);
      u64 v[4];
#pragma unroll
      for (int b = 0; b < 4; ++b)
        v[b] = __hip_atomic_load(src + (b * 512 + D0) / 2, __ATOMIC_RELAXED,
                                 __HIP_MEMORY_SCOPE_AGENT);
      // unpack payloads; split hi/lo bf16 into A rows (swizzled LDS writes)
      unsigned cb = (unsigned)(D0 * 2);
#pragma unroll
      for (int b = 0; b < 4; ++b) {
        float f0 = __uint_as_float((unsigned)v[b]);          // dim D0
        float f1 = __uint_as_float((unsigned)(v[b] >> 32));  // dim D0+1
        bf16 h0 = f2b(f0), h1 = f2b(f1);
        float r0 = f0 - b2f(h0), r1 = f1 - b2f(h1);
        bf16 e0 = f2b(r0), e1 = f2b(r1);
        unsigned hi = (unsigned)*(unsigned short*)&h0 |
                      ((unsigned)*(unsigned short*)&h1 << 16);
        unsigned lo = (unsigned)*(unsigned short*)&e0 |
                      ((unsigned)*(unsigned short*)&e1 << 16);
        *(unsigned*)(pl + (((unsigned)(b * 1024) + cb) ^ (unsigned)(b << 4))) = hi;
        *(unsigned*)(pl + (((unsigned)((b + 4) * 1024) + cb) ^ (unsigned)((b + 4) << 4))) = lo;
      }
    }
    __syncthreads();  // barrier 1: LDS A-operand ready
    // prefetch xv for step s+1 NOW: retires under MFMA + cell + next acquire
    float xvn[4];
    if (l < 16) {
      int sn = s + 1;
#pragma unroll
      for (int b = 0; b < 4; ++b) {
        int lb = len_s[b];
        int rt = bwd ? (lb - 1 - sn) : sn;
        if (sn >= lb) rt = 0;
        xvn[b] = xg_d[((size_t)b * tmax + rt) * G4_ + grow];
      }
    }
    // 16 MFMA over full K, 2 interleaved chains (8-deep dependency each)
    floatx4 accA = (floatx4){0.f, 0.f, 0.f, 0.f};
    floatx4 accB = (floatx4){0.f, 0.f, 0.f, 0.f};
#pragma unroll
    for (int k2 = 0; k2 < 16; k2 += 2) {
      short8 a0 = *(const short8*)(pl + ((rbyte + (unsigned)(k2 * 64)) ^ rsw));
      short8 a1 = *(const short8*)(pl + ((rbyte + (unsigned)((k2 + 1) * 64)) ^ rsw));
      accA = __builtin_amdgcn_mfma_f32_16x16x32_bf16(a0, bfr[k2], accA, 0, 0, 0);
      accB = __builtin_amdgcn_mfma_f32_16x16x32_bf16(a1, bfr[k2 + 1], accB, 0, 0, 0);
    }
    floatx4 acc = accA + accB;
    // fold lo partial (lanes 16-31 hold C rows 4-7), add xg, in-wave cell
    float hout = 0.f;
#pragma unroll
    for (int r = 0; r < 4; ++r) {
      float v2 = acc[r] + __shfl(acc[r], col + 16, 64);
      if (l < 16) v2 += xv[r];
      float gi = __shfl(v2, sb + 0, 64);
      float gf = __shfl(v2, sb + 1, 64);
      float gg = __shfl(v2, sb + 2, 64);
      float go = __shfl(v2, sb + 3, 64);
      if (l < 16 && (l & 3) == r && s < len_s[r]) {
        cst = sigm_(gf) * cst + sigm_(gi) * tanh_(gg);
        hout = sigm_(go) * tanh_(cst);
      }
    }
    // publish payload (ALWAYS — padded batches publish 0, counter gates use)
    if (l < 16) {
      int b = l & 3;
      __hip_atomic_store(pay + p * 2048 + b * 512 + dim, hout,
                         __ATOMIC_RELAXED, __HIP_MEMORY_SCOPE_AGENT);
    }
    __syncthreads();  // barrier 2: pre-barrier vmcnt(0) drains ALL publishes
    if (tid == 0)
      __hip_atomic_fetch_add(cnt, 1u, __ATOMIC_RELAXED, __HIP_MEMORY_SCOPE_AGENT);
    // HBM activation store off the handoff path (overlaps next acquire spin)
    if (l < 16) {
      int b = l & 3;
      if (s < len_s[b]) {
        int t = bwd ? (len_s[b] - 1 - s) : s;
        outp[((size_t)b * tmax + t) * ostride + ocol + dim] = f2b(hout);
      }
    }
#pragma unroll
    for (int b = 0; b < 4; ++b) xv[b] = xvn[b];
  }
}

// ---------------- joint (<=48KB LDS): block = 64 rows x 256 cols, K=512.
__global__ __launch_bounds__(256) void joint_kernel(
    const float* __restrict__ ea, const float* __restrict__ da,
    const float* __restrict__ Wp, const float* __restrict__ pb,
    const int* __restrict__ targets,
    float* __restrict__ blankraw, float* __restrict__ labraw,
    float* __restrict__ jstats) {
  __shared__ __align__(16) bf16 As[64][72];
  __shared__ __align__(16) bf16 Bs[256][72];
  __shared__ float bias_s[256];
  __shared__ int tgt_s[64];
  __shared__ float pstat[64][2][2];

  int tid = threadIdx.x;
  int tile = blockIdx.x, cb = blockIdx.y, b = blockIdx.z;
  int r0 = tile * 64;

  bias_s[tid & 255] = pb[cb * 256 + (tid & 255)];
  if (tid < 64) {
    int r = r0 + tid;
    int u = r % U1_;
    tgt_s[tid] = (r < RPB_ && u < U_) ? targets[b * U_ + u] : -1;
  }
  int si = tid >> 2;
  int sseg = (tid & 3) * 16;
  int sr = r0 + si;
  bool svalid = sr < RPB_;
  int st = svalid ? sr / U1_ : 0;
  int su = svalid ? sr % U1_ : 0;
  const float* ep = ea + ((size_t)(b * T_ + st)) * 512 + sseg;
  const float* dp = da + ((size_t)(b * U1_ + su)) * 512 + sseg;

  int wid = tid >> 6, l = tid & 63;
  int wm = wid >> 1, wn = wid & 1;
  int l4 = l & 15, lq = l >> 4;

  floatx4 acc[2][8];
#pragma unroll
  for (int ms = 0; ms < 2; ++ms)
#pragma unroll
    for (int nt = 0; nt < 8; ++nt) acc[ms][nt] = (floatx4){0.f, 0.f, 0.f, 0.f};

  for (int k0 = 0; k0 < 512; k0 += 64) {
    __syncthreads();
    {
      const float* e = ep + k0;
      const float* d = dp + k0;
#pragma unroll
      for (int h = 0; h < 2; ++h) {
        float4 e0 = *(const float4*)(e + h * 8);
        float4 e1 = *(const float4*)(e + h * 8 + 4);
        float4 d0 = *(const float4*)(d + h * 8);
        float4 d1 = *(const float4*)(d + h * 8 + 4);
        short8 pk = {0, 0, 0, 0, 0, 0, 0, 0};
        if (svalid) {
          pk[0] = bf16bits(tanh_(e0.x + d0.x));
          pk[1] = bf16bits(tanh_(e0.y + d0.y));
          pk[2] = bf16bits(tanh_(e0.z + d0.z));
          pk[3] = bf16bits(tanh_(e0.w + d0.w));
          pk[4] = bf16bits(tanh_(e1.x + d1.x));
          pk[5] = bf16bits(tanh_(e1.y + d1.y));
          pk[6] = bf16bits(tanh_(e1.z + d1.z));
          pk[7] = bf16bits(tanh_(e1.w + d1.w));
        }
        *(short8*)(&As[si][sseg + h * 8]) = pk;
      }
    }
#pragma unroll
    for (int q = 0; q < 8; ++q) {
      int cc = tid + q * 256;
      int r = cc >> 3, kc = (cc & 7) * 8;
      const float* wp = Wp + (size_t)(cb * 256 + r) * 512 + k0 + kc;
      float4 w0 = *(const float4*)(wp);
      float4 w1 = *(const float4*)(wp + 4);
      *(short8*)(&Bs[r][kc]) = pack8(w0, w1);
    }
    __syncthreads();
#pragma unroll
    for (int kk = 0; kk < 64; kk += 32) {
      short8 af[2], bf8[8];
#pragma unroll
      for (int ms = 0; ms < 2; ++ms)
        af[ms] = *(const short8*)(&As[wm * 32 + ms * 16 + l4][kk + lq * 8]);
#pragma unroll
      for (int nt = 0; nt < 8; ++nt)
        bf8[nt] = *(const short8*)(&Bs[wn * 128 + nt * 16 + l4][kk + lq * 8]);
#pragma unroll
      for (int ms = 0; ms < 2; ++ms)
#pragma unroll
        for (int nt = 0; nt < 8; ++nt)
          acc[ms][nt] = __builtin_amdgcn_mfma_f32_16x16x32_bf16(af[ms], bf8[nt], acc[ms][nt], 0, 0, 0);
    }
  }
#pragma unroll
  for (int ms = 0; ms < 2; ++ms) {
#pragma unroll
    for (int r = 0; r < 4; ++r) {
      int i = wm * 32 + ms * 16 + lq * 4 + r;
      int grow = r0 + i;
      bool valid = grow < RPB_;
      int tg = tgt_s[i];
      float v[8];
      float mx = -1e30f;
#pragma unroll
      for (int nt = 0; nt < 8; ++nt) {
        int colc = wn * 128 + nt * 16 + l4;
        float x = acc[ms][nt][r] + bias_s[colc];
        v[nt] = x;
        mx = fmaxf(mx, x);
        int gcol = cb * 256 + colc;
        if (valid) {
          if (gcol == 0) blankraw[(size_t)b * RPB_ + grow] = x;
          if (gcol == tg) labraw[(size_t)b * RPB_ + grow] = x;
        }
      }
#pragma unroll
      for (int dd = 1; dd < 16; dd <<= 1) mx = fmaxf(mx, __shfl_xor(mx, dd, 64));
      float se = 0.f;
#pragma unroll
      for (int nt = 0; nt < 8; ++nt) se += __expf(v[nt] - mx);
#pragma unroll
      for (int dd = 1; dd < 16; dd <<= 1) se += __shfl_xor(se, dd, 64);
      if (l4 == 0) { pstat[i][wn][0] = mx; pstat[i][wn][1] = se; }
    }
  }
  __syncthreads();
  if (tid < 64) {
    float ma = pstat[tid][0][0], sa = pstat[tid][0][1];
    float mb = pstat[tid][1][0], sb = pstat[tid][1][1];
    float mc = fmaxf(ma, mb);
    float sc = sa * __expf(ma - mc) + sb * __expf(mb - mc);
    size_t o = (((size_t)b * RPAD_ + r0 + tid) * 4 + cb) * 2;
    jstats[o] = mc;
    jstats[o + 1] = sc;
  }
}

// ---------------- finalize: merge 4 col-block stats -> lse; convert raw logits to log-probs
__global__ void finalize_kernel(const float* __restrict__ jstats,
                                float* __restrict__ blank, float* __restrict__ lab) {
  int g = blockIdx.x * 256 + threadIdx.x;
  if (g >= B_ * RPB_) return;
  int b = g / RPB_, r = g % RPB_;
  const float* st = jstats + ((size_t)b * RPAD_ + r) * 8;
  float M = fmaxf(fmaxf(st[0], st[2]), fmaxf(st[4], st[6]));
  float s = st[1] * __expf(st[0] - M) + st[3] * __expf(st[2] - M) +
            st[5] * __expf(st[4] - M) + st[7] * __expf(st[6] - M);
  float lse = M + __logf(s);
  blank[g] -= lse;
  if ((r % U1_) < U_) lab[g] -= lse;
}

// ---------------- RNNT loss (OUTPUT IS FLOAT32)
__global__ void loss_kernel(const float* __restrict__ blank, const float* __restrict__ lab,
                            const int* __restrict__ Tl, const int* __restrict__ Ul,
                            float* __restrict__ outp) {
  int b = threadIdx.x >> 6;
  int l = threadIdx.x & 63;
  int TL = Tl[b], UL = Ul[b];
  float alpha_l = 0.f, alpha0 = 0.f;
  for (int t = 0; t < TL; ++t) {
    float a_u0, a_l1;
    if (t == 0) { a_u0 = 0.f; a_l1 = -1e30f; }
    else {
      const float* bl = blank + ((size_t)b * T_ + (t - 1)) * U1_;
      a_u0 = alpha0 + bl[0];
      a_l1 = alpha_l + bl[l + 1];
    }
    const float* lb = lab + ((size_t)b * T_ + t) * U1_;
    float C = lb[l];
#pragma unroll
    for (int dd = 1; dd < 64; dd <<= 1) {
      float o = __shfl_up(C, dd, 64);
      if (l >= dd) C += o;
    }
    float S = a_l1 - C;
#pragma unroll
    for (int dd = 1; dd < 64; dd <<= 1) {
      float o = __shfl_up(S, dd, 64);
      if (l >= dd) S = lae_(S, o);
    }
    alpha_l = C + lae_(a_u0, S);
    alpha0 = a_u0;
  }
  float av = (UL == 0) ? alpha0 : __shfl(alpha_l, UL - 1, 64);
  float ll = av + blank[((size_t)b * T_ + (TL - 1)) * U1_ + UL];
  __shared__ float lls[4];
  if (l == 0) lls[b] = ll;
  __syncthreads();
  if (threadIdx.x == 0) outp[0] = -0.25f * (lls[0] + lls[1] + lls[2] + lls[3]);
}

// ---------------- workspace layout (bytes)
static constexpr size_t OFF_XG = 0;                                        // f32 [2][4][300][2048]
static constexpr size_t OFF_XA = OFF_XG + (size_t)2 * B_ * T_ * G4_ * 4;   // bf16 [4][300][1024]
static constexpr size_t OFF_XB = OFF_XA + (size_t)B_ * T_ * 1024 * 2;
static constexpr size_t OFF_ENC = OFF_XB + (size_t)B_ * T_ * 1024 * 2;     // bf16 [4][300][512]
static constexpr size_t OFF_EA = OFF_ENC + (size_t)B_ * T_ * 512 * 2;      // f32
static constexpr size_t OFF_DEMB = OFF_EA + (size_t)B_ * T_ * 512 * 4;     // bf16
static constexpr size_t OFF_DXG = OFF_DEMB + (size_t)B_ * U1_ * 512 * 2;   // f32
static constexpr size_t OFF_DH = OFF_DXG + (size_t)B_ * U1_ * G4_ * 4;     // bf16
static constexpr size_t OFF_DEC = OFF_DH + (size_t)B_ * U1_ * 512 * 2;     // bf16
static constexpr size_t OFF_DA = OFF_DEC + (size_t)B_ * U1_ * 512 * 2;     // f32
static constexpr size_t OFF_BL = OFF_DA + (size_t)B_ * U1_ * 512 * 4;      // f32 [4][300][65]
static constexpr size_t OFF_LAB = OFF_BL + (size_t)B_ * T_ * U1_ * 4;
static constexpr size_t OFF_HPK = OFF_LAB + (size_t)B_ * T_ * U1_ * 4;     // f32 [7][2][4][512] payloads
static constexpr size_t OFF_CNT = OFF_HPK + (size_t)7 * 4096 * 4;          // u32 [7][64] counters
static constexpr size_t OFF_JST = OFF_HPK + (size_t)7 * 4096 * 8;          // f32 [4][19520][4][2]

extern "C" void kernel_launch(void* const* d_in, const int* in_sizes, int n_in,
                              void* d_out, int out_size, void* d_ws, size_t ws_size,
                              hipStream_t stream) {
  (void)in_sizes; (void)n_in; (void)out_size; (void)ws_size;
  const float* inputs = (const float*)d_in[0];
  const int* inputs_length = (const int*)d_in[1];
  const int* targets = (const int*)d_in[2];
  const int* targets_length = (const int*)d_in[3];
  const float* enc_Wih = (const float*)d_in[4];
  const float* enc_Whh = (const float*)d_in[5];
  const float* enc_b = (const float*)d_in[6];
  const float* enc_proj_W = (const float*)d_in[7];
  const float* enc_proj_b = (const float*)d_in[8];
  const float* dec_emb = (const float*)d_in[9];
  const float* dec_Wih = (const float*)d_in[10];
  const float* dec_Whh = (const float*)d_in[11];
  const float* dec_b = (const float*)d_in[12];
  const float* dec_proj_W = (const float*)d_in[13];
  const float* dec_proj_b = (const float*)d_in[14];
  const float* j_fwd_W = (const float*)d_in[15];
  const float* j_fwd_b = (const float*)d_in[16];
  const float* j_proj_W = (const float*)d_in[17];
  const float* j_proj_b = (const float*)d_in[18];

  char* ws = (char*)d_ws;
  float* xg = (float*)(ws + OFF_XG);
  bf16* xa = (bf16*)(ws + OFF_XA);
  bf16* xb = (bf16*)(ws + OFF_XB);
  bf16* encb = (bf16*)(ws + OFF_ENC);
  float* eab = (float*)(ws + OFF_EA);
  bf16* demb = (bf16*)(ws + OFF_DEMB);
  float* dxg = (float*)(ws + OFF_DXG);
  bf16* dh = (bf16*)(ws + OFF_DH);
  bf16* decb = (bf16*)(ws + OFF_DEC);
  float* dab = (float*)(ws + OFF_DA);
  float* blank = (float*)(ws + OFF_BL);
  float* lab = (float*)(ws + OFF_LAB);
  float* hpay = (float*)(ws + OFF_HPK);
  unsigned* hcnt = (unsigned*)(ws + OFF_CNT);
  float* jstats = (float*)(ws + OFF_JST);

  zero_hpk_kernel<<<112, 256, 0, stream>>>(hpay, hcnt);
  prep_kernel<<<600, 256, 0, stream>>>(inputs, xa);
  embed_kernel<<<520, 256, 0, stream>>>(dec_emb, targets, demb);

  // pre-scan GEMMs: decoder xg, then encoder layer-0 xg (both dirs)
  gemm_kernel<<<dim3(5, 32), 256, 0, stream>>>(demb, 512, dec_Wih, 512, dec_b,
                                               dxg, 1, G4_, B_ * U1_, 512);
  for (int dd = 0; dd < 2; ++dd) {
    gemm_kernel<<<dim3(19, 32), 256, 0, stream>>>(
        xa, 1024, enc_Wih + (size_t)dd * G4_ * 1024, 1024, enc_b + (size_t)dd * G4_,
        xg + (size_t)dd * B_ * T_ * G4_, 1, G4_, B_ * T_, 128);
  }
  // fused scan: dirs 0,1 = encoder layer 0; dir 2 = decoder (slots 0..2)
  scan_kernel<<<dim3(NW_, 3), 256, 0, stream>>>(
      xg, enc_Whh, inputs_length, 0, T_, 2, xb, 1024,
      2, dxg, dec_Whh, targets_length, 1, U1_, dh, 512,
      hpay, hcnt);

  // decoder tail
  gemm_kernel<<<dim3(5, 8), 256, 0, stream>>>(dh, 512, dec_proj_W, 512, dec_proj_b,
                                              decb, 0, 512, B_ * U1_, 512);
  gemm_kernel<<<dim3(5, 8), 256, 0, stream>>>(decb, 512, j_fwd_W + 512, 1024, j_fwd_b,
                                              dab, 1, 512, B_ * U1_, 512);

  // encoder layers 1,2 (slots 3,4 and 5,6)
  bf16* xcur = xb;
  for (int lyr = 1; lyr < 3; ++lyr) {
    bf16* xnext = (xcur == xa) ? xb : xa;
    for (int dd = 0; dd < 2; ++dd) {
      gemm_kernel<<<dim3(19, 32), 256, 0, stream>>>(
          xcur, 1024,
          enc_Wih + (size_t)(lyr * 2 + dd) * G4_ * 1024, 1024,
          enc_b + (size_t)(lyr * 2 + dd) * G4_,
          xg + (size_t)dd * B_ * T_ * G4_, 1, G4_, B_ * T_, 1024);
    }
    scan_kernel<<<dim3(NW_, 2), 256, 0, stream>>>(
        xg, enc_Whh + (size_t)lyr * 2 * G4_ * H_,
        inputs_length, 0, T_, 2, xnext, 1024,
        -1, dxg, dec_Whh, targets_length, 1, U1_, dh, 512,
        hpay + (size_t)(3 + 2 * (lyr - 1)) * 4096,
        hcnt + (size_t)(3 + 2 * (lyr - 1)) * 64);
    xcur = xnext;
  }
  gemm_kernel<<<dim3(19, 8), 256, 0, stream>>>(xcur, 1024, enc_proj_W, 1024, enc_proj_b,
                                               encb, 0, 512, B_ * T_, 1024);
  gemm_kernel<<<dim3(19, 8), 256, 0, stream>>>(encb, 512, j_fwd_W, 1024, (const float*)nullptr,
                                               eab, 1, 512, B_ * T_, 512);

  joint_kernel<<<dim3(NTILE_, 4, B_), 256, 0, stream>>>(eab, dab, j_proj_W, j_proj_b, targets,
                                                        blank, lab, jstats);
  finalize_kernel<<<(B_ * RPB_ + 255) / 256, 256, 0, stream>>>(jstats, blank, lab);
  loss_kernel<<<1, 256, 0, stream>>>(blank, lab, inputs_length, targets_length, (float*)d_out);
}

// Round 9
// 3336.392 us; speedup vs baseline: 1.2788x; 1.2788x over previous
//
#include <hip/hip_runtime.h>
#include <hip/hip_bf16.h>

#define B_ 4
#define T_ 300
#define U_ 64
#define U1_ 65
#define V_ 1024
#define H_ 512
#define G4_ 2048
#define NW_ 32
#define RPB_ (T_ * U1_)   // 19500 rows per batch in joint
#define NTILE_ 305        // ceil(19500/64)
#define RPAD_ 19520       // NTILE_*64

typedef __hip_bfloat16 bf16;
typedef unsigned long long u64;
typedef __attribute__((ext_vector_type(8))) short short8;
typedef __attribute__((ext_vector_type(4))) float floatx4;

__device__ __forceinline__ float b2f(bf16 x) { return __bfloat162float(x); }
__device__ __forceinline__ bf16 f2b(float x) { return __float2bfloat16(x); }
__device__ __forceinline__ short bf16bits(float x) {
  bf16 h = __float2bfloat16(x);
  return *reinterpret_cast<short*>(&h);
}
__device__ __forceinline__ short8 pack8(float4 a, float4 b) {
  short8 p;
  p[0] = bf16bits(a.x); p[1] = bf16bits(a.y); p[2] = bf16bits(a.z); p[3] = bf16bits(a.w);
  p[4] = bf16bits(b.x); p[5] = bf16bits(b.y); p[6] = bf16bits(b.z); p[7] = bf16bits(b.w);
  return p;
}
__device__ __forceinline__ float sigm_(float x) { return 1.f / (1.f + __expf(-x)); }
__device__ __forceinline__ float tanh_(float x) { return 1.f - 2.f / (1.f + __expf(2.f * x)); }
__device__ __forceinline__ float lae_(float x, float y) {
  float m = fmaxf(x, y);
  float n = fminf(x, y);
  return m + __logf(1.f + __expf(n - m));
}

// ---------------- zero packet region (stale stamps from prior launches)
__global__ void zero_hpk_kernel(u64* __restrict__ a) {
  int i = blockIdx.x * 256 + threadIdx.x;
  if (i < 7 * 4096) a[i] = 0ull;
}

// ---------------- prepack a f32 weight matrix to bf16 (one-time, same f2b
// rounding the per-block pack8 used -> bit-identical results)
__global__ void packw_kernel(const float* __restrict__ W, bf16* __restrict__ Wb, int n) {
  int i = blockIdx.x * 256 + threadIdx.x;
  if (i < n) Wb[i] = f2b(W[i]);
}

// ---------------- prep: pad layer-0 input (80 -> 128 cols of a 1024-stride buf)
__global__ void prep_kernel(const float* __restrict__ in, bf16* __restrict__ x0) {
  int i = blockIdx.x * 256 + threadIdx.x;
  if (i < B_ * T_ * 128) {
    int k = i & 127;
    int row = i >> 7;
    float v = (k < 80) ? in[row * 80 + k] : 0.f;
    x0[(size_t)row * 1024 + k] = f2b(v);
  }
}

// ---------------- embedding gather (f32 table -> bf16)
__global__ void embed_kernel(const float* __restrict__ emb, const int* __restrict__ tgt,
                             bf16* __restrict__ demb) {
  int i = blockIdx.x * 256 + threadIdx.x;
  if (i >= B_ * U1_ * 512) return;
  int k = i & 511;
  int bu = i >> 9;
  int u = bu % U1_, b = bu / U1_;
  int id = (u == 0) ? 0 : tgt[b * U_ + u - 1];
  demb[i] = f2b(emb[(size_t)id * 512 + k]);
}

// ---------------- bf16-A x f32-W MFMA GEMM: C[M x (grid.y*64)] = A[M,K] @ W[N,K]^T + bias
__global__ __launch_bounds__(256) void gemm_kernel(
    const bf16* __restrict__ A, int lda,
    const float* __restrict__ W, int ldw,
    const float* __restrict__ bias,
    void* __restrict__ Cout, int out_f32, int ldc,
    int M, int K) {
  __shared__ __align__(16) bf16 As[64][72];
  __shared__ __align__(16) bf16 Bs[64][72];
  int m0 = blockIdx.x * 64, n0 = blockIdx.y * 64;
  int tid = threadIdx.x, w = tid >> 6, l = tid & 63;
  int l4 = l & 15, lq = l >> 4;
  floatx4 acc[4];
#pragma unroll
  for (int nt = 0; nt < 4; ++nt) acc[nt] = (floatx4){0.f, 0.f, 0.f, 0.f};
  for (int k0 = 0; k0 < K; k0 += 64) {
    __syncthreads();
#pragma unroll
    for (int q = 0; q < 2; ++q) {
      int cc = tid + q * 256;
      int r = cc >> 3, kc = (cc & 7) * 8;
      short8 va = {0, 0, 0, 0, 0, 0, 0, 0};
      int gm = m0 + r;
      if (gm < M) va = *(const short8*)(A + (size_t)gm * lda + k0 + kc);
      *(short8*)(&As[r][kc]) = va;
      const float* wp = W + (size_t)(n0 + r) * ldw + k0 + kc;
      float4 w0 = *(const float4*)(wp);
      float4 w1 = *(const float4*)(wp + 4);
      *(short8*)(&Bs[r][kc]) = pack8(w0, w1);
    }
    __syncthreads();
#pragma unroll
    for (int kk = 0; kk < 64; kk += 32) {
      short8 a = *(const short8*)(&As[w * 16 + l4][kk + lq * 8]);
#pragma unroll
      for (int nt = 0; nt < 4; ++nt) {
        short8 bb = *(const short8*)(&Bs[nt * 16 + l4][kk + lq * 8]);
        acc[nt] = __builtin_amdgcn_mfma_f32_16x16x32_bf16(a, bb, acc[nt], 0, 0, 0);
      }
    }
  }
#pragma unroll
  for (int nt = 0; nt < 4; ++nt) {
    int col = n0 + nt * 16 + l4;
    float bv = bias ? bias[col] : 0.f;
#pragma unroll
    for (int r = 0; r < 4; ++r) {
      int row = m0 + w * 16 + lq * 4 + r;
      if (row < M) {
        float v = acc[nt][r] + bv;
        if (out_f32) ((float*)Cout)[(size_t)row * ldc + col] = v;
        else ((bf16*)Cout)[(size_t)row * ldc + col] = f2b(v);
      }
    }
  }
}

// ---------------- persistent LSTM scan (R6, verified 816us/dispatch — DO NOT
// TOUCH). grid = (NW_, ndir). WG w owns h-dims [w*16,+16) x 4 gates; wave sub
// = one 16-col MFMA tile over full K=512. h split hi+lo bf16 into A-rows
// {0-3,4-7}: one 16-MFMA pass computes (h_hi+h_lo) @ bf16(Whh) in f32
// accumulation. Packets: u64 {h_f32, stamp s+1}, parity double-buffered,
// agent-scope relaxed atomics (compiler-precise waits), hot spin on exact
// stamp, ALWAYS published. xv gate-input loads double-buffered post-barrier
// (keeps HBM latency off the poll wait — the verified R6 win).
__global__ __launch_bounds__(256, 1) void scan_kernel(
    const float* __restrict__ xg,      // [ndir][B][Tmax][2048] f32
    const float* __restrict__ whh,     // [ndir][2048][512] f32
    const int* __restrict__ len_raw, int len_add,
    int Tmax, int bwd_mask,
    bf16* __restrict__ out, int out_stride,
    int dec_d,
    const float* __restrict__ xg2, const float* __restrict__ whh2,
    const int* __restrict__ len_raw2, int len_add2,
    int Tmax2, bf16* __restrict__ out2, int out_stride2,
    u64* __restrict__ hpk) {
  int w = blockIdx.x, d = blockIdx.y;
  int tid = threadIdx.x;
  bool isdec = (d == dec_d);
  const float* xg_d = isdec ? xg2 : xg + (size_t)d * B_ * Tmax * G4_;
  const float* whh_d = isdec ? whh2 : whh + (size_t)d * G4_ * H_;
  const int* lens = isdec ? len_raw2 : len_raw;
  int ladd = isdec ? len_add2 : len_add;
  int tmax = isdec ? Tmax2 : Tmax;
  bf16* outp = isdec ? out2 : out;
  int ostride = isdec ? out_stride2 : out_stride;
  int ocol = isdec ? 0 : d * H_;
  bool bwd = isdec ? false : ((bwd_mask >> d) & 1);
  u64* hp = hpk + (size_t)d * 4096;

  int sub = tid >> 6;          // wave index 0..3
  int l = tid & 63;
  int col = l & 15;            // MFMA output column (gate-row within wave tile)
  int lq = l >> 4;
  int gate = col & 3;          // col -> gate-major mapping: grow = gate*512+dim
  int dloc = col >> 2;
  int dim = w * 16 + sub * 4 + dloc;
  int grow = gate * H_ + dim;
  int sb = l & 12;             // shuffle base: lanes sb..sb+3 = 4 gates of one dim

  __shared__ int len_s[4];
  // A operand: rows 0-3 = h_hi (batch), rows 4-7 = h_lo (batch), rows 8-15 = 0.
  __shared__ __align__(16) bf16 h_lds[2][16][512];

  if (tid < 4) len_s[tid] = lens[tid] + ladd;
  {
    unsigned* hz = (unsigned*)&h_lds[0][0][0];
#pragma unroll
    for (int i = 0; i < 32; ++i) hz[tid + i * 256] = 0u;
  }

  // B fragments: Whh row 'grow' as bf16, 16 K-steps x 8 elems (64 VGPRs)
  short8 bfr[16];
  {
    const float* wp = whh_d + (size_t)grow * H_ + lq * 8;
#pragma unroll
    for (int ks2 = 0; ks2 < 16; ++ks2) {
      float4 w0 = *(const float4*)(wp + ks2 * 32);
      float4 w1 = *(const float4*)(wp + ks2 * 32 + 4);
      bfr[ks2] = pack8(w0, w1);
    }
  }
  __syncthreads();
  int smax = max(max(len_s[0], len_s[1]), max(len_s[2], len_s[3]));

  int D0 = sub * 128 + 2 * l;  // this lane polls dims D0, D0+1 (adjacent)
  float cst = 0.f;             // cell state for (dim, batch = l&3) on lanes<16
  char* hbase = (char*)&h_lds[0][0][0];
  unsigned rsw = (unsigned)((l & 7) << 4);                 // read XOR swizzle
  unsigned rbyte = (unsigned)((l & 15) * 1024 + lq * 16);  // A-frag base byte

  // xv prologue for s=0 (gate input, all 4 batches, lanes<16)
  float xv[4];
  if (l < 16) {
#pragma unroll
    for (int b = 0; b < 4; ++b) {
      int lb = len_s[b];
      int rt = bwd ? (lb - 1) : 0;
      xv[b] = xg_d[((size_t)b * tmax + rt) * G4_ + grow];
    }
  }

  for (int s = 0; s < smax; ++s) {
    int p = s & 1;
    char* pl = hbase + p * 16384;
    // acquire my slice of h(s-1): poll packets directly (stamp==s => fresh).
    if (s > 0) {
      const u64* src = hp + ((s - 1) & 1) * 2048;
      u64 v[8];
      for (;;) {
        bool ok = true;
#pragma unroll
        for (int b = 0; b < 4; ++b) {
          v[2 * b] = __hip_atomic_load(src + b * 512 + D0, __ATOMIC_RELAXED,
                                       __HIP_MEMORY_SCOPE_AGENT);
          v[2 * b + 1] = __hip_atomic_load(src + b * 512 + D0 + 1, __ATOMIC_RELAXED,
                                           __HIP_MEMORY_SCOPE_AGENT);
          ok &= ((int)(unsigned)v[2 * b] == s) & ((int)(unsigned)v[2 * b + 1] == s);
        }
        if (__all(ok)) break;  // hot spin: 8-load round trip is natural backoff
      }
      // unpack payloads; split hi/lo bf16 into A rows (swizzled LDS writes)
      unsigned cb = (unsigned)(D0 * 2);
#pragma unroll
      for (int b = 0; b < 4; ++b) {
        float f0 = __uint_as_float((unsigned)(v[2 * b] >> 32));
        float f1 = __uint_as_float((unsigned)(v[2 * b + 1] >> 32));
        bf16 h0 = f2b(f0), h1 = f2b(f1);
        float r0 = f0 - b2f(h0), r1 = f1 - b2f(h1);
        bf16 e0 = f2b(r0), e1 = f2b(r1);
        unsigned hi = (unsigned)*(unsigned short*)&h0 |
                      ((unsigned)*(unsigned short*)&h1 << 16);
        unsigned lo = (unsigned)*(unsigned short*)&e0 |
                      ((unsigned)*(unsigned short*)&e1 << 16);
        *(unsigned*)(pl + (((unsigned)(b * 1024) + cb) ^ (unsigned)(b << 4))) = hi;
        *(unsigned*)(pl + (((unsigned)((b + 4) * 1024) + cb) ^ (unsigned)((b + 4) << 4))) = lo;
      }
    }
    __syncthreads();  // the ONLY per-step barrier
    // prefetch xv for step s+1 NOW: retires under MFMA + cell + next acquire
    float xvn[4];
    if (l < 16) {
      int sn = s + 1;
#pragma unroll
      for (int b = 0; b < 4; ++b) {
        int lb = len_s[b];
        int rt = bwd ? (lb - 1 - sn) : sn;
        if (sn >= lb) rt = 0;
        xvn[b] = xg_d[((size_t)b * tmax + rt) * G4_ + grow];
      }
    }
    // 16 MFMA over full K, 2 interleaved chains (8-deep dependency each)
    floatx4 accA = (floatx4){0.f, 0.f, 0.f, 0.f};
    floatx4 accB = (floatx4){0.f, 0.f, 0.f, 0.f};
#pragma unroll
    for (int k2 = 0; k2 < 16; k2 += 2) {
      short8 a0 = *(const short8*)(pl + ((rbyte + (unsigned)(k2 * 64)) ^ rsw));
      short8 a1 = *(const short8*)(pl + ((rbyte + (unsigned)((k2 + 1) * 64)) ^ rsw));
      accA = __builtin_amdgcn_mfma_f32_16x16x32_bf16(a0, bfr[k2], accA, 0, 0, 0);
      accB = __builtin_amdgcn_mfma_f32_16x16x32_bf16(a1, bfr[k2 + 1], accB, 0, 0, 0);
    }
    floatx4 acc = accA + accB;
    // fold lo partial (lanes 16-31 hold C rows 4-7), add xg, in-wave cell
    float hout = 0.f;
#pragma unroll
    for (int r = 0; r < 4; ++r) {
      float v2 = acc[r] + __shfl(acc[r], col + 16, 64);
      if (l < 16) v2 += xv[r];
      float gi = __shfl(v2, sb + 0, 64);
      float gf = __shfl(v2, sb + 1, 64);
      float gg = __shfl(v2, sb + 2, 64);
      float go = __shfl(v2, sb + 3, 64);
      if (l < 16 && (l & 3) == r && s < len_s[r]) {
        cst = sigm_(gf) * cst + sigm_(gi) * tanh_(gg);
        hout = sigm_(go) * tanh_(cst);
      }
    }
    // publish stamped packet FIRST (ALWAYS), then the HBM activation store
    if (l < 16) {
      int b = l & 3;
      u64 pkt = ((u64)__float_as_uint(hout) << 32) | (unsigned)(s + 1);
      __hip_atomic_store(hp + p * 2048 + b * 512 + dim, pkt,
                         __ATOMIC_RELAXED, __HIP_MEMORY_SCOPE_AGENT);
      if (s < len_s[b]) {
        int t = bwd ? (len_s[b] - 1 - s) : s;
        outp[((size_t)b * tmax + t) * ostride + ocol + dim] = f2b(hout);
      }
    }
#pragma unroll
    for (int b = 0; b < 4; ++b) xv[b] = xvn[b];
  }
}

// ---------------- joint, restructured: grid (NTILE_, B_); cb loop INSIDE.
// Per block: tanh'd As tile (64 rows x full K=512) computed ONCE into LDS
// (was recomputed 4x across cb blocks), then 4 column-blocks of 256 staged
// from PREPACKED bf16 j_proj_W (was f32 + per-thread pack8 = VALU-bound).
// LDS = 66.5K As + 37K Bs + misc ~ 106KB -> 1 block/CU.
__global__ __launch_bounds__(256) void joint_kernel(
    const float* __restrict__ ea, const float* __restrict__ da,
    const bf16* __restrict__ Wpb, const float* __restrict__ pb,
    const int* __restrict__ targets,
    float* __restrict__ blankraw, float* __restrict__ labraw,
    float* __restrict__ jstats) {
  __shared__ __align__(16) bf16 As[64][520];
  __shared__ __align__(16) bf16 Bs[256][72];
  __shared__ float bias_s[256];
  __shared__ int tgt_s[64];
  __shared__ float pstat[64][2][2];

  int tid = threadIdx.x;
  int tile = blockIdx.x, b = blockIdx.y;
  int r0 = tile * 64;

  if (tid < 64) {
    int r = r0 + tid;
    int u = r % U1_;
    tgt_s[tid] = (r < RPB_ && u < U_) ? targets[b * U_ + u] : -1;
  }
  int si = tid >> 2;
  int sseg = (tid & 3) * 16;
  int sr = r0 + si;
  bool svalid = sr < RPB_;
  int st = svalid ? sr / U1_ : 0;
  int su = svalid ? sr % U1_ : 0;
  const float* ep = ea + ((size_t)(b * T_ + st)) * 512 + sseg;
  const float* dp = da + ((size_t)(b * U1_ + su)) * 512 + sseg;

  // ---- stage As ONCE: full K=512, tanh(e+d) fused, bf16
#pragma unroll
  for (int k0s = 0; k0s < 512; k0s += 64) {
    const float* e = ep + k0s;
    const float* d = dp + k0s;
#pragma unroll
    for (int h = 0; h < 2; ++h) {
      float4 e0 = *(const float4*)(e + h * 8);
      float4 e1 = *(const float4*)(e + h * 8 + 4);
      float4 d0 = *(const float4*)(d + h * 8);
      float4 d1 = *(const float4*)(d + h * 8 + 4);
      short8 pk = {0, 0, 0, 0, 0, 0, 0, 0};
      if (svalid) {
        pk[0] = bf16bits(tanh_(e0.x + d0.x));
        pk[1] = bf16bits(tanh_(e0.y + d0.y));
        pk[2] = bf16bits(tanh_(e0.z + d0.z));
        pk[3] = bf16bits(tanh_(e0.w + d0.w));
        pk[4] = bf16bits(tanh_(e1.x + d1.x));
        pk[5] = bf16bits(tanh_(e1.y + d1.y));
        pk[6] = bf16bits(tanh_(e1.z + d1.z));
        pk[7] = bf16bits(tanh_(e1.w + d1.w));
      }
      *(short8*)(&As[si][k0s + sseg + h * 8]) = pk;
    }
  }

  int wid = tid >> 6, l = tid & 63;
  int wm = wid >> 1, wn = wid & 1;
  int l4 = l & 15, lq = l >> 4;

  for (int cb = 0; cb < 4; ++cb) {
    bias_s[tid] = pb[cb * 256 + tid];

    floatx4 acc[2][8];
#pragma unroll
    for (int ms = 0; ms < 2; ++ms)
#pragma unroll
      for (int nt = 0; nt < 8; ++nt) acc[ms][nt] = (floatx4){0.f, 0.f, 0.f, 0.f};

    for (int k0 = 0; k0 < 512; k0 += 64) {
      __syncthreads();  // protects Bs reuse (and As fill on first pass)
#pragma unroll
      for (int q = 0; q < 8; ++q) {
        int cc = tid + q * 256;
        int r = cc >> 3, kc = (cc & 7) * 8;
        *(short8*)(&Bs[r][kc]) =
            *(const short8*)(Wpb + (size_t)(cb * 256 + r) * 512 + k0 + kc);
      }
      __syncthreads();
#pragma unroll
      for (int kk = 0; kk < 64; kk += 32) {
        short8 af[2], bf8[8];
#pragma unroll
        for (int ms = 0; ms < 2; ++ms)
          af[ms] = *(const short8*)(&As[wm * 32 + ms * 16 + l4][k0 + kk + lq * 8]);
#pragma unroll
        for (int nt = 0; nt < 8; ++nt)
          bf8[nt] = *(const short8*)(&Bs[wn * 128 + nt * 16 + l4][kk + lq * 8]);
#pragma unroll
        for (int ms = 0; ms < 2; ++ms)
#pragma unroll
          for (int nt = 0; nt < 8; ++nt)
            acc[ms][nt] = __builtin_amdgcn_mfma_f32_16x16x32_bf16(af[ms], bf8[nt], acc[ms][nt], 0, 0, 0);
      }
    }
#pragma unroll
    for (int ms = 0; ms < 2; ++ms) {
#pragma unroll
      for (int r = 0; r < 4; ++r) {
        int i = wm * 32 + ms * 16 + lq * 4 + r;
        int grow = r0 + i;
        bool valid = grow < RPB_;
        int tg = tgt_s[i];
        float v[8];
        float mx = -1e30f;
#pragma unroll
        for (int nt = 0; nt < 8; ++nt) {
          int colc = wn * 128 + nt * 16 + l4;
          float x = acc[ms][nt][r] + bias_s[colc];
          v[nt] = x;
          mx = fmaxf(mx, x);
          int gcol = cb * 256 + colc;
          if (valid) {
            if (gcol == 0) blankraw[(size_t)b * RPB_ + grow] = x;
            if (gcol == tg) labraw[(size_t)b * RPB_ + grow] = x;
          }
        }
#pragma unroll
        for (int dd = 1; dd < 16; dd <<= 1) mx = fmaxf(mx, __shfl_xor(mx, dd, 64));
        float se = 0.f;
#pragma unroll
        for (int nt = 0; nt < 8; ++nt) se += __expf(v[nt] - mx);
#pragma unroll
        for (int dd = 1; dd < 16; dd <<= 1) se += __shfl_xor(se, dd, 64);
        if (l4 == 0) { pstat[i][wn][0] = mx; pstat[i][wn][1] = se; }
      }
    }
    __syncthreads();
    if (tid < 64) {
      float ma = pstat[tid][0][0], sa = pstat[tid][0][1];
      float mb = pstat[tid][1][0], sb = pstat[tid][1][1];
      float mc = fmaxf(ma, mb);
      float sc = sa * __expf(ma - mc) + sb * __expf(mb - mc);
      size_t o = (((size_t)b * RPAD_ + r0 + tid) * 4 + cb) * 2;
      jstats[o] = mc;
      jstats[o + 1] = sc;
    }
  }
}

// ---------------- finalize: merge 4 col-block stats -> lse; convert raw logits to log-probs
__global__ void finalize_kernel(const float* __restrict__ jstats,
                                float* __restrict__ blank, float* __restrict__ lab) {
  int g = blockIdx.x * 256 + threadIdx.x;
  if (g >= B_ * RPB_) return;
  int b = g / RPB_, r = g % RPB_;
  const float* st = jstats + ((size_t)b * RPAD_ + r) * 8;
  float M = fmaxf(fmaxf(st[0], st[2]), fmaxf(st[4], st[6]));
  float s = st[1] * __expf(st[0] - M) + st[3] * __expf(st[2] - M) +
            st[5] * __expf(st[4] - M) + st[7] * __expf(st[6] - M);
  float lse = M + __logf(s);
  blank[g] -= lse;
  if ((r % U1_) < U_) lab[g] -= lse;
}

// ---------------- RNNT loss (OUTPUT IS FLOAT32)
__global__ void loss_kernel(const float* __restrict__ blank, const float* __restrict__ lab,
                            const int* __restrict__ Tl, const int* __restrict__ Ul,
                            float* __restrict__ outp) {
  int b = threadIdx.x >> 6;
  int l = threadIdx.x & 63;
  int TL = Tl[b], UL = Ul[b];
  float alpha_l = 0.f, alpha0 = 0.f;
  for (int t = 0; t < TL; ++t) {
    float a_u0, a_l1;
    if (t == 0) { a_u0 = 0.f; a_l1 = -1e30f; }
    else {
      const float* bl = blank + ((size_t)b * T_ + (t - 1)) * U1_;
      a_u0 = alpha0 + bl[0];
      a_l1 = alpha_l + bl[l + 1];
    }
    const float* lb = lab + ((size_t)b * T_ + t) * U1_;
    float C = lb[l];
#pragma unroll
    for (int dd = 1; dd < 64; dd <<= 1) {
      float o = __shfl_up(C, dd, 64);
      if (l >= dd) C += o;
    }
    float S = a_l1 - C;
#pragma unroll
    for (int dd = 1; dd < 64; dd <<= 1) {
      float o = __shfl_up(S, dd, 64);
      if (l >= dd) S = lae_(S, o);
    }
    alpha_l = C + lae_(a_u0, S);
    alpha0 = a_u0;
  }
  float av = (UL == 0) ? alpha0 : __shfl(alpha_l, UL - 1, 64);
  float ll = av + blank[((size_t)b * T_ + (TL - 1)) * U1_ + UL];
  __shared__ float lls[4];
  if (l == 0) lls[b] = ll;
  __syncthreads();
  if (threadIdx.x == 0) outp[0] = -0.25f * (lls[0] + lls[1] + lls[2] + lls[3]);
}

// ---------------- workspace layout (bytes)
static constexpr size_t OFF_XG = 0;                                        // f32 [2][4][300][2048]
static constexpr size_t OFF_XA = OFF_XG + (size_t)2 * B_ * T_ * G4_ * 4;   // bf16 [4][300][1024]
static constexpr size_t OFF_XB = OFF_XA + (size_t)B_ * T_ * 1024 * 2;
static constexpr size_t OFF_ENC = OFF_XB + (size_t)B_ * T_ * 1024 * 2;     // bf16 [4][300][512]
static constexpr size_t OFF_EA = OFF_ENC + (size_t)B_ * T_ * 512 * 2;      // f32
static constexpr size_t OFF_DEMB = OFF_EA + (size_t)B_ * T_ * 512 * 4;     // bf16
static constexpr size_t OFF_DXG = OFF_DEMB + (size_t)B_ * U1_ * 512 * 2;   // f32
static constexpr size_t OFF_DH = OFF_DXG + (size_t)B_ * U1_ * G4_ * 4;     // bf16
static constexpr size_t OFF_DEC = OFF_DH + (size_t)B_ * U1_ * 512 * 2;     // bf16
static constexpr size_t OFF_DA = OFF_DEC + (size_t)B_ * U1_ * 512 * 2;     // f32
static constexpr size_t OFF_BL = OFF_DA + (size_t)B_ * U1_ * 512 * 4;      // f32 [4][300][65]
static constexpr size_t OFF_LAB = OFF_BL + (size_t)B_ * T_ * U1_ * 4;
static constexpr size_t OFF_HPK = OFF_LAB + (size_t)B_ * T_ * U1_ * 4;     // u64 [7][2][4][512] packets
static constexpr size_t OFF_JST = OFF_HPK + (size_t)7 * 4096 * 8;          // f32 [4][19520][4][2]
static constexpr size_t OFF_WPB = OFF_JST + (size_t)B_ * RPAD_ * 4 * 2 * 4; // bf16 [1024][512] j_proj_W

extern "C" void kernel_launch(void* const* d_in, const int* in_sizes, int n_in,
                              void* d_out, int out_size, void* d_ws, size_t ws_size,
                              hipStream_t stream) {
  (void)in_sizes; (void)n_in; (void)out_size; (void)ws_size;
  const float* inputs = (const float*)d_in[0];
  const int* inputs_length = (const int*)d_in[1];
  const int* targets = (const int*)d_in[2];
  const int* targets_length = (const int*)d_in[3];
  const float* enc_Wih = (const float*)d_in[4];
  const float* enc_Whh = (const float*)d_in[5];
  const float* enc_b = (const float*)d_in[6];
  const float* enc_proj_W = (const float*)d_in[7];
  const float* enc_proj_b = (const float*)d_in[8];
  const float* dec_emb = (const float*)d_in[9];
  const float* dec_Wih = (const float*)d_in[10];
  const float* dec_Whh = (const float*)d_in[11];
  const float* dec_b = (const float*)d_in[12];
  const float* dec_proj_W = (const float*)d_in[13];
  const float* dec_proj_b = (const float*)d_in[14];
  const float* j_fwd_W = (const float*)d_in[15];
  const float* j_fwd_b = (const float*)d_in[16];
  const float* j_proj_W = (const float*)d_in[17];
  const float* j_proj_b = (const float*)d_in[18];

  char* ws = (char*)d_ws;
  float* xg = (float*)(ws + OFF_XG);
  bf16* xa = (bf16*)(ws + OFF_XA);
  bf16* xb = (bf16*)(ws + OFF_XB);
  bf16* encb = (bf16*)(ws + OFF_ENC);
  float* eab = (float*)(ws + OFF_EA);
  bf16* demb = (bf16*)(ws + OFF_DEMB);
  float* dxg = (float*)(ws + OFF_DXG);
  bf16* dh = (bf16*)(ws + OFF_DH);
  bf16* decb = (bf16*)(ws + OFF_DEC);
  float* dab = (float*)(ws + OFF_DA);
  float* blank = (float*)(ws + OFF_BL);
  float* lab = (float*)(ws + OFF_LAB);
  u64* hpk = (u64*)(ws + OFF_HPK);
  float* jstats = (float*)(ws + OFF_JST);
  bf16* wpb = (bf16*)(ws + OFF_WPB);

  zero_hpk_kernel<<<112, 256, 0, stream>>>(hpk);
  packw_kernel<<<2048, 256, 0, stream>>>(j_proj_W, wpb, V_ * 512);
  prep_kernel<<<600, 256, 0, stream>>>(inputs, xa);
  embed_kernel<<<520, 256, 0, stream>>>(dec_emb, targets, demb);

  // pre-scan GEMMs: decoder xg, then encoder layer-0 xg (both dirs)
  gemm_kernel<<<dim3(5, 32), 256, 0, stream>>>(demb, 512, dec_Wih, 512, dec_b,
                                               dxg, 1, G4_, B_ * U1_, 512);
  for (int dd = 0; dd < 2; ++dd) {
    gemm_kernel<<<dim3(19, 32), 256, 0, stream>>>(
        xa, 1024, enc_Wih + (size_t)dd * G4_ * 1024, 1024, enc_b + (size_t)dd * G4_,
        xg + (size_t)dd * B_ * T_ * G4_, 1, G4_, B_ * T_, 128);
  }
  // fused scan: dirs 0,1 = encoder layer 0; dir 2 = decoder (packet slots 0..2)
  scan_kernel<<<dim3(NW_, 3), 256, 0, stream>>>(
      xg, enc_Whh, inputs_length, 0, T_, 2, xb, 1024,
      2, dxg, dec_Whh, targets_length, 1, U1_, dh, 512,
      hpk);

  // decoder tail
  gemm_kernel<<<dim3(5, 8), 256, 0, stream>>>(dh, 512, dec_proj_W, 512, dec_proj_b,
                                              decb, 0, 512, B_ * U1_, 512);
  gemm_kernel<<<dim3(5, 8), 256, 0, stream>>>(decb, 512, j_fwd_W + 512, 1024, j_fwd_b,
                                              dab, 1, 512, B_ * U1_, 512);

  // encoder layers 1,2 (packet slots 3,4 and 5,6)
  bf16* xcur = xb;
  for (int lyr = 1; lyr < 3; ++lyr) {
    bf16* xnext = (xcur == xa) ? xb : xa;
    for (int dd = 0; dd < 2; ++dd) {
      gemm_kernel<<<dim3(19, 32), 256, 0, stream>>>(
          xcur, 1024,
          enc_Wih + (size_t)(lyr * 2 + dd) * G4_ * 1024, 1024,
          enc_b + (size_t)(lyr * 2 + dd) * G4_,
          xg + (size_t)dd * B_ * T_ * G4_, 1, G4_, B_ * T_, 1024);
    }
    scan_kernel<<<dim3(NW_, 2), 256, 0, stream>>>(
        xg, enc_Whh + (size_t)lyr * 2 * G4_ * H_,
        inputs_length, 0, T_, 2, xnext, 1024,
        -1, dxg, dec_Whh, targets_length, 1, U1_, dh, 512,
        hpk + (size_t)(3 + 2 * (lyr - 1)) * 4096);
    xcur = xnext;
  }
  gemm_kernel<<<dim3(19, 8), 256, 0, stream>>>(xcur, 1024, enc_proj_W, 1024, enc_proj_b,
                                               encb, 0, 512, B_ * T_, 1024);
  gemm_kernel<<<dim3(19, 8), 256, 0, stream>>>(encb, 512, j_fwd_W, 1024, (const float*)nullptr,
                                               eab, 1, 512, B_ * T_, 512);

  joint_kernel<<<dim3(NTILE_, B_), 256, 0, stream>>>(eab, dab, wpb, j_proj_b, targets,
                                                     blank, lab, jstats);
  finalize_kernel<<<(B_ * RPB_ + 255) / 256, 256, 0, stream>>>(jstats, blank, lab);
  loss_kernel<<<1, 256, 0, stream>>>(blank, lab, inputs_length, targets_length, (float*)d_out);
}